// Round 3
// baseline (441.324 us; speedup 1.0000x reference)
//
#include <hip/hip_runtime.h>
#include <math.h>

// Fused separable-Gaussian SSIM. N=32,C=3,H=W=512 fp32.
// Windows (5,11),(11,5),(11,11), sigma=1.5, zero padding.
// Moments m={x,y,xx,yy,xy}. Vertical pass: register rolling window, raw
// exponential weights accumulated as inner(5 central taps)+outer(6 taps);
//   V5 = inner*(1/S5), V11 = (inner+outer)*(1/S11)  (g5 == central g11 shape).
// Horizontal: A(5,11)=g11h(V5); C(11,11) & B(11,5) share inner/outer over V11.
// H phase reads LDS as float4, 4 output cols per thread (160 B/px LDS reads).

#define H 512
#define W 512
#define NPLANE 96
#define TW 128          // output cols per block
#define PW 138          // TW + 10 halo cols
#define PWP 140         // padded LDS row (rows are 560B = 35*16B, b128-safe)
#define BAND 256        // output rows per block
#define R 8             // rows per barrier iteration
#define NITER (BAND / R)
#define NTHREADS 256    // 4 waves; H phase has exactly 256 slots

struct GaussW {
  float w11[11];  // normalized 11-tap Gaussian (fp64-normalized, cast fp32)
  float e[11];    // raw exp(-d^2/4.5) weights, fp32
  float r5, r11;  // 1/S5, 1/S11
};

__device__ __forceinline__ float ssim_val(float mu1, float mu2, float m11,
                                          float m22, float m12) {
  const float C1 = 0.0001f;   // 0.01^2
  const float C2 = 0.0009f;   // 0.03^2
  float mu1s = mu1 * mu1, mu2s = mu2 * mu2, mu12 = mu1 * mu2;
  float num = (2.0f * mu12 + C1) * (2.0f * (m12 - mu12) + C2);
  float den = (mu1s + mu2s + C1) * ((m11 - mu1s) + (m22 - mu2s) + C2);
  return num / den;
}

__global__ __launch_bounds__(NTHREADS) void ssim_kernel(
    const float* __restrict__ img1, const float* __restrict__ img2,
    double* __restrict__ acc, GaussW w) {
  // channel-major: [sub][ch][col]; ch 0..4 = V5 moments, 5..9 = V11 moments
  __shared__ __align__(16) float sV[R][10][PWP];   // 44.8 KB
  __shared__ double red[NTHREADS / 64];

  const int t = threadIdx.x;
  const int tile = blockIdx.x, band = blockIdx.y, plane = blockIdx.z;
  const float* p1 = img1 + (size_t)plane * H * W;
  const float* p2 = img2 + (size_t)plane * H * W;
  const int c0 = tile * TW;
  const int r0 = band * BAND;
  const int col = c0 + t - 5;            // column owned in V phase
  const bool vact = (t < PW);
  const bool colok = vact && ((unsigned)col < (unsigned)W);

  // rolling raw-input window: xb[k] holds row (r-5+k) for current output row r
  float xb[11], yb[11];
#pragma unroll
  for (int k = 0; k < 10; ++k) {
    int rr = r0 - 5 + k;
    bool ok = colok && (rr >= 0);
    xb[k] = ok ? p1[rr * W + col] : 0.0f;
    yb[k] = ok ? p2[rr * W + col] : 0.0f;
  }

  double accT = 0.0;
  for (int it = 0; it < NITER; ++it) {
    const int rbase = r0 + it * R;
    // ---- V phase: each column-thread produces R rows x 10 moment channels
    if (vact) {
#pragma unroll
      for (int sub = 0; sub < R; ++sub) {
        const int rr = rbase + sub + 5;
        bool ok = colok && (rr < H);
        xb[10] = ok ? p1[rr * W + col] : 0.0f;
        yb[10] = ok ? p2[rr * W + col] : 0.0f;
        float i0 = 0, i1 = 0, i2 = 0, i3 = 0, i4 = 0;
        float o0 = 0, o1 = 0, o2 = 0, o3 = 0, o4 = 0;
#pragma unroll
        for (int k = 0; k < 11; ++k) {
          float x = xb[k], y = yb[k], ek = w.e[k];
          float ex = ek * x, ey = ek * y;
          if (k >= 3 && k <= 7) {
            i0 += ex; i1 += ey;
            i2 = fmaf(ex, x, i2); i3 = fmaf(ey, y, i3); i4 = fmaf(ex, y, i4);
          } else {
            o0 += ex; o1 += ey;
            o2 = fmaf(ex, x, o2); o3 = fmaf(ey, y, o3); o4 = fmaf(ex, y, o4);
          }
        }
        sV[sub][0][t] = i0 * w.r5;
        sV[sub][1][t] = i1 * w.r5;
        sV[sub][2][t] = i2 * w.r5;
        sV[sub][3][t] = i3 * w.r5;
        sV[sub][4][t] = i4 * w.r5;
        sV[sub][5][t] = (i0 + o0) * w.r11;
        sV[sub][6][t] = (i1 + o1) * w.r11;
        sV[sub][7][t] = (i2 + o2) * w.r11;
        sV[sub][8][t] = (i3 + o3) * w.r11;
        sV[sub][9][t] = (i4 + o4) * w.r11;
#pragma unroll
        for (int k = 0; k < 10; ++k) { xb[k] = xb[k + 1]; yb[k] = yb[k + 1]; }
      }
    }
    __syncthreads();

    // ---- H phase: 256 slots (R rows x 32 groups x 4 cols), 1 per thread
    {
      const int sub = t >> 5;
      const int cb = (t & 31) * 4;       // first of 4 output cols (16B aligned)
      float a[4][5], b[4][5], c[4][5];

      // combo A = normalized g11 horizontally over V5 channels
#pragma unroll
      for (int ch = 0; ch < 5; ++ch) {
        const float4* vp = (const float4*)&sV[sub][ch][cb];
        float f[16];
#pragma unroll
        for (int q = 0; q < 4; ++q) {
          float4 v = vp[q];
          f[4 * q] = v.x; f[4 * q + 1] = v.y;
          f[4 * q + 2] = v.z; f[4 * q + 3] = v.w;
        }
#pragma unroll
        for (int k = 0; k < 4; ++k) {
          float s = 0;
#pragma unroll
          for (int j = 0; j < 11; ++j) s = fmaf(w.w11[j], f[k + j], s);
          a[k][ch] = s;
        }
      }
      // combos C (g11h) and B (g5h) share raw inner/outer sums over V11
#pragma unroll
      for (int ch = 0; ch < 5; ++ch) {
        const float4* vp = (const float4*)&sV[sub][5 + ch][cb];
        float f[16];
#pragma unroll
        for (int q = 0; q < 4; ++q) {
          float4 v = vp[q];
          f[4 * q] = v.x; f[4 * q + 1] = v.y;
          f[4 * q + 2] = v.z; f[4 * q + 3] = v.w;
        }
#pragma unroll
        for (int k = 0; k < 4; ++k) {
          float ih = 0, oh = 0;
#pragma unroll
          for (int j = 0; j < 11; ++j) {
            if (j >= 3 && j <= 7) ih = fmaf(w.e[j], f[k + j], ih);
            else                  oh = fmaf(w.e[j], f[k + j], oh);
          }
          c[k][ch] = (ih + oh) * w.r11;
          b[k][ch] = ih * w.r5;
        }
      }
      float iterSum = 0.0f;
#pragma unroll
      for (int k = 0; k < 4; ++k) {
        iterSum += ssim_val(a[k][0], a[k][1], a[k][2], a[k][3], a[k][4]);
        iterSum += ssim_val(b[k][0], b[k][1], b[k][2], b[k][3], b[k][4]);
        iterSum += ssim_val(c[k][0], c[k][1], c[k][2], c[k][3], c[k][4]);
      }
      accT += (double)iterSum;
    }
    __syncthreads();
  }

  // block reduction (4 waves) -> one device atomic per block
#pragma unroll
  for (int off = 32; off > 0; off >>= 1) accT += __shfl_down(accT, off);
  const int wid = t >> 6;
  if ((t & 63) == 0) red[wid] = accT;
  __syncthreads();
  if (t == 0) {
    double s = 0.0;
    for (int k = 0; k < NTHREADS / 64; ++k) s += red[k];
    atomicAdd(acc, s);
  }
}

__global__ void finalize_kernel(const double* __restrict__ acc,
                                float* __restrict__ out) {
  out[0] = (float)(acc[0] * (1.0 / (3.0 * (double)NPLANE * H * W)));
}

extern "C" void kernel_launch(void* const* d_in, const int* in_sizes, int n_in,
                              void* d_out, int out_size, void* d_ws,
                              size_t ws_size, hipStream_t stream) {
  const float* img1 = (const float*)d_in[0];
  const float* img2 = (const float*)d_in[1];
  float* out = (float*)d_out;
  double* acc = (double*)d_ws;

  hipMemsetAsync(acc, 0, sizeof(double), stream);

  GaussW w;
  {
    double e64[11], S11 = 0.0, S5 = 0.0;
    for (int i = 0; i < 11; ++i) {
      double d = (double)(i - 5);
      e64[i] = exp(-d * d / 4.5);   // 2*sigma^2 = 4.5
      S11 += e64[i];
      if (i >= 3 && i <= 7) S5 += e64[i];
    }
    for (int i = 0; i < 11; ++i) {
      w.w11[i] = (float)(e64[i] / S11);
      w.e[i] = (float)e64[i];
    }
    w.r5 = (float)(1.0 / S5);
    w.r11 = (float)(1.0 / S11);
  }

  dim3 grid(W / TW, H / BAND, NPLANE);   // 4 x 2 x 96 = 768 blocks (3/CU)
  ssim_kernel<<<grid, NTHREADS, 0, stream>>>(img1, img2, acc, w);
  finalize_kernel<<<1, 1, 0, stream>>>(acc, out);
}

// Round 5
// 386.914 us; speedup vs baseline: 1.1406x; 1.1406x over previous
//
#include <hip/hip_runtime.h>
#include <math.h>

// Fused separable-Gaussian SSIM. N=32,C=3,H=W=512 fp32.
// Windows (5,11),(11,5),(11,11), sigma=1.5, zero padding.
// Vertical pass stores RAW conv sums (exp weights, no normalization):
//   inner = central-5-tap raw sum (== g5 shape), outer = remaining 6 taps;
//   V5raw = inner, V11raw = inner+outer.
// Horizontal pass computes raw 2D sums, then scales each combo's 5 outputs by
// its true normalizer product (sA = 1/(S5*S11) for A,B; sC = 1/S11^2 for C)
// BEFORE the SSIM rational — all five quantities scale linearly, so this is
// exactly the reference computation.  (Round-4 lesson: sigma terms are NOT
// homogeneous in the scale, so constant-folding the normalizer is invalid.)

#define H 512
#define W 512
#define NPLANE 96
#define TW 128          // output cols per block
#define PW 138          // TW + 10 halo cols
#define PWP 140         // padded LDS row (560B = 35*16B, b128-aligned)
#define BAND 256        // output rows per block
#define R 8             // rows per barrier iteration
#define NITER (BAND / R)
#define NTHREADS 256    // 4 waves; H phase has exactly 256 slots

struct GaussW {
  float e[11];    // raw exp(-d^2/4.5) weights
  float sA, sC;   // normalizer products: 1/(S5*S11), 1/(S11*S11)
};

__device__ __forceinline__ float ssim_val(float mu1, float mu2, float m11,
                                          float m22, float m12) {
  const float C1 = 0.0001f;   // 0.01^2
  const float C2 = 0.0009f;   // 0.03^2
  float mu12 = mu1 * mu2;
  float num = fmaf(2.0f, mu12, C1) * fmaf(2.0f, m12 - mu12, C2);
  float d1 = fmaf(mu2, mu2, fmaf(mu1, mu1, C1));
  float d2 = fmaf(-mu2, mu2, fmaf(-mu1, mu1, (m11 + m22) + C2));
  return num * __builtin_amdgcn_rcpf(d1 * d2);  // den > 0 always
}

__global__ __launch_bounds__(NTHREADS, 3) void ssim_kernel(
    const float* __restrict__ img1, const float* __restrict__ img2,
    double* __restrict__ acc, GaussW w) {
  // channel-major: [sub][ch][col]; ch 0..4 = V5raw, 5..9 = V11raw
  __shared__ __align__(16) float sV[R][10][PWP];   // 44.8 KB -> 3 blocks/CU
  __shared__ double red[NTHREADS / 64];

  const int t = threadIdx.x;
  const int tile = blockIdx.x, band = blockIdx.y, plane = blockIdx.z;
  const float* p1 = img1 + (size_t)plane * H * W;
  const float* p2 = img2 + (size_t)plane * H * W;
  const int c0 = tile * TW;
  const int r0 = band * BAND;
  const int col = c0 + t - 5;            // column owned in V phase
  const bool vact = (t < PW);
  const bool colok = vact && ((unsigned)col < (unsigned)W);

  // rolling moment windows: slot k holds row (r-5+k) for current output row r
  float mx[11], my[11], mxx[11], myy[11], mxy[11];
#pragma unroll
  for (int k = 0; k < 10; ++k) {
    int rr = r0 - 5 + k;
    bool ok = colok && (rr >= 0);
    float x = ok ? p1[rr * W + col] : 0.0f;
    float y = ok ? p2[rr * W + col] : 0.0f;
    mx[k] = x; my[k] = y;
    mxx[k] = x * x; myy[k] = y * y; mxy[k] = x * y;
  }

  double accT = 0.0;
  for (int it = 0; it < NITER; ++it) {
    const int rbase = r0 + it * R;
    // ---- V phase: each column-thread produces R rows x 10 raw channels
    if (vact) {
      float nx[R], ny[R];
#pragma unroll
      for (int sub = 0; sub < R; ++sub) {          // batch loads up-front
        const int rr = rbase + sub + 5;
        bool ok = colok && (rr < H);
        nx[sub] = ok ? p1[rr * W + col] : 0.0f;
        ny[sub] = ok ? p2[rr * W + col] : 0.0f;
      }
#pragma unroll
      for (int sub = 0; sub < R; ++sub) {
        float x = nx[sub], y = ny[sub];
        mx[10] = x; my[10] = y;
        mxx[10] = x * x; myy[10] = y * y; mxy[10] = x * y;
        float i0 = 0, i1 = 0, i2 = 0, i3 = 0, i4 = 0;
        float o0 = 0, o1 = 0, o2 = 0, o3 = 0, o4 = 0;
#pragma unroll
        for (int k = 0; k < 11; ++k) {
          float ek = w.e[k];
          if (k >= 3 && k <= 7) {
            i0 = fmaf(ek, mx[k], i0);  i1 = fmaf(ek, my[k], i1);
            i2 = fmaf(ek, mxx[k], i2); i3 = fmaf(ek, myy[k], i3);
            i4 = fmaf(ek, mxy[k], i4);
          } else {
            o0 = fmaf(ek, mx[k], o0);  o1 = fmaf(ek, my[k], o1);
            o2 = fmaf(ek, mxx[k], o2); o3 = fmaf(ek, myy[k], o3);
            o4 = fmaf(ek, mxy[k], o4);
          }
        }
        sV[sub][0][t] = i0;
        sV[sub][1][t] = i1;
        sV[sub][2][t] = i2;
        sV[sub][3][t] = i3;
        sV[sub][4][t] = i4;
        sV[sub][5][t] = i0 + o0;
        sV[sub][6][t] = i1 + o1;
        sV[sub][7][t] = i2 + o2;
        sV[sub][8][t] = i3 + o3;
        sV[sub][9][t] = i4 + o4;
#pragma unroll
        for (int k = 0; k < 10; ++k) {             // shift (renamed by unroll)
          mx[k] = mx[k + 1]; my[k] = my[k + 1];
          mxx[k] = mxx[k + 1]; myy[k] = myy[k + 1]; mxy[k] = mxy[k + 1];
        }
      }
    }
    __syncthreads();

    // ---- H phase: 256 slots (R rows x 32 groups x 4 cols), 1 per thread
    {
      const int sub = t >> 5;
      const int cb = (t & 31) * 4;     // first of 4 output cols (16B aligned)
      float iterSum = 0.0f;

      // Combo A: raw 11-tap conv over V5raw channels, scale by sA, SSIM
      {
        float a[4][5];
#pragma unroll
        for (int ch = 0; ch < 5; ++ch) {
          const float4* vp = (const float4*)&sV[sub][ch][cb];
          float f[16];
#pragma unroll
          for (int q = 0; q < 4; ++q) {
            float4 v = vp[q];
            f[4 * q] = v.x; f[4 * q + 1] = v.y;
            f[4 * q + 2] = v.z; f[4 * q + 3] = v.w;
          }
#pragma unroll
          for (int k = 0; k < 4; ++k) {
            float s = 0;
#pragma unroll
            for (int j = 0; j < 11; ++j) s = fmaf(w.e[j], f[k + j], s);
            a[k][ch] = s * w.sA;
          }
        }
#pragma unroll
        for (int k = 0; k < 4; ++k)
          iterSum += ssim_val(a[k][0], a[k][1], a[k][2], a[k][3], a[k][4]);
      }
      // Combos C (full 11 raw) and B (inner 5 raw) share sums over V11raw
      {
        float bi[4][5], co[4][5];
#pragma unroll
        for (int ch = 0; ch < 5; ++ch) {
          const float4* vp = (const float4*)&sV[sub][5 + ch][cb];
          float f[16];
#pragma unroll
          for (int q = 0; q < 4; ++q) {
            float4 v = vp[q];
            f[4 * q] = v.x; f[4 * q + 1] = v.y;
            f[4 * q + 2] = v.z; f[4 * q + 3] = v.w;
          }
#pragma unroll
          for (int k = 0; k < 4; ++k) {
            float ih = 0, oh = 0;
#pragma unroll
            for (int j = 0; j < 11; ++j) {
              if (j >= 3 && j <= 7) ih = fmaf(w.e[j], f[k + j], ih);
              else                  oh = fmaf(w.e[j], f[k + j], oh);
            }
            bi[k][ch] = ih * w.sA;          // B true scale = 1/(S11*S5)
            co[k][ch] = (ih + oh) * w.sC;   // C true scale = 1/S11^2
          }
        }
#pragma unroll
        for (int k = 0; k < 4; ++k) {
          iterSum += ssim_val(co[k][0], co[k][1], co[k][2], co[k][3], co[k][4]);
          iterSum += ssim_val(bi[k][0], bi[k][1], bi[k][2], bi[k][3], bi[k][4]);
        }
      }
      accT += (double)iterSum;
    }
    __syncthreads();
  }

  // block reduction (4 waves) -> one device atomic per block
#pragma unroll
  for (int off = 32; off > 0; off >>= 1) accT += __shfl_down(accT, off);
  const int wid = t >> 6;
  if ((t & 63) == 0) red[wid] = accT;
  __syncthreads();
  if (t == 0) {
    double s = 0.0;
    for (int k = 0; k < NTHREADS / 64; ++k) s += red[k];
    atomicAdd(acc, s);
  }
}

__global__ void finalize_kernel(const double* __restrict__ acc,
                                float* __restrict__ out) {
  out[0] = (float)(acc[0] * (1.0 / (3.0 * (double)NPLANE * H * W)));
}

extern "C" void kernel_launch(void* const* d_in, const int* in_sizes, int n_in,
                              void* d_out, int out_size, void* d_ws,
                              size_t ws_size, hipStream_t stream) {
  const float* img1 = (const float*)d_in[0];
  const float* img2 = (const float*)d_in[1];
  float* out = (float*)d_out;
  double* acc = (double*)d_ws;

  hipMemsetAsync(acc, 0, sizeof(double), stream);

  GaussW w;
  {
    double e64[11], S11 = 0.0, S5 = 0.0;
    for (int i = 0; i < 11; ++i) {
      double d = (double)(i - 5);
      e64[i] = exp(-d * d / 4.5);   // 2*sigma^2 = 4.5
      S11 += e64[i];
      if (i >= 3 && i <= 7) S5 += e64[i];
    }
    for (int i = 0; i < 11; ++i) w.e[i] = (float)e64[i];
    w.sA = (float)(1.0 / (S5 * S11));    // combos A and B
    w.sC = (float)(1.0 / (S11 * S11));   // combo C
  }

  dim3 grid(W / TW, H / BAND, NPLANE);   // 4 x 2 x 96 = 768 blocks (3/CU)
  ssim_kernel<<<grid, NTHREADS, 0, stream>>>(img1, img2, acc, w);
  finalize_kernel<<<1, 1, 0, stream>>>(acc, out);
}

// Round 8
// 331.154 us; speedup vs baseline: 1.3327x; 1.1684x over previous
//
#include <hip/hip_runtime.h>
#include <math.h>

// Fused separable-Gaussian SSIM. N=32,C=3,H=W=512 fp32.
// Windows (5,11),(11,5),(11,11), sigma=1.5, zero padding.
// u/v reformulation: u=x+y, v=x-y. SSIM per pixel needs only the 4 smoothed
// channels {u, v, u^2, v^2}:
//   mu1*mu2       = (mu_u^2 - mu_v^2)/4
//   mu1^2+mu2^2   = (mu_u^2 + mu_v^2)/2
//   m12 - mu1mu2  = ((Muu-Mvv) - (mu_u^2-mu_v^2))/4
//   m11+m22-mus   = ((Muu+Mvv) - (mu_u^2+mu_v^2))/2
// Vertical pass stores RAW conv sums (exp weights): inner (central 5 taps,
// == g5 shape) and full = inner+outer. Horizontal pass computes raw 2D sums;
// the normalizer s is folded EXACTLY into the SSIM rational coefficients
// (k1=.5*s^2 multiplies quadratic terms, k2=.5*s the linear ones).

#define H 512
#define W 512
#define NPLANE 96
#define TW 128          // output cols per block
#define PW 138          // TW + 10 halo cols
#define PWP 140         // padded LDS row (560B = 35*16B, b128-aligned)
#define BAND 128        // output rows per block
#define R 8             // rows per barrier iteration
#define NITER (BAND / R)
#define NTHREADS 256    // 4 waves; H phase has exactly 256 slots

struct GaussW {
  float e[11];                  // raw exp(-d^2/4.5) weights
  float k2A, k1A, k2C, k1C;     // .5*s, .5*s^2 for combos A/B and C
};

__device__ __forceinline__ float ssim_uv(float au, float av, float auu,
                                         float avv, float k2, float k1) {
  const float C1 = 0.0001f;   // 0.01^2
  const float C2 = 0.0009f;   // 0.03^2
  float P = au * au, Q = av * av;
  float t1 = P - Q, t2 = P + Q;
  float n1 = fmaf(k1, t1, C1);
  float d1 = fmaf(k1, t2, C1);
  float u1 = auu - avv, u2 = auu + avv;
  float n2 = fmaf(k2, u1, fmaf(-k1, t1, C2));
  float d2 = fmaf(k2, u2, fmaf(-k1, t2, C2));
  return (n1 * n2) * __builtin_amdgcn_rcpf(d1 * d2);  // den >= C1*C2 > 0
}

__global__ __launch_bounds__(NTHREADS, 4) void ssim_kernel(
    const float* __restrict__ img1, const float* __restrict__ img2,
    double* __restrict__ acc, GaussW w) {
  // channel-major: [sub][ch][col]; ch 0..3 = inner{u,v,uu,vv}, 4..7 = full
  __shared__ __align__(16) float sV[R][8][PWP];   // 35.8 KB -> 4 blocks/CU
  __shared__ double red[NTHREADS / 64];

  const int t = threadIdx.x;
  const int tile = blockIdx.x, band = blockIdx.y, plane = blockIdx.z;
  const float* p1 = img1 + (size_t)plane * H * W;
  const float* p2 = img2 + (size_t)plane * H * W;
  const int c0 = tile * TW;
  const int r0 = band * BAND;
  const int col = c0 + t - 5;            // column owned in V phase
  const bool vact = (t < PW);
  const bool colok = vact && ((unsigned)col < (unsigned)W);

  // rolling windows of {u, v, u^2, v^2}: slot k = row (r-5+k) for output row r
  float wu[11], wv[11], wuu[11], wvv[11];
#pragma unroll
  for (int k = 0; k < 10; ++k) {
    int rr = r0 - 5 + k;
    bool ok = colok && (rr >= 0);
    float x = ok ? p1[rr * W + col] : 0.0f;
    float y = ok ? p2[rr * W + col] : 0.0f;
    float u = x + y, v = x - y;
    wu[k] = u; wv[k] = v; wuu[k] = u * u; wvv[k] = v * v;
  }

  double accT = 0.0;
  for (int it = 0; it < NITER; ++it) {
    const int rbase = r0 + it * R;
    // ---- V phase: each column-thread produces R rows x 8 raw channels
    if (vact) {
      float nx[R], ny[R];
#pragma unroll
      for (int sub = 0; sub < R; ++sub) {          // batch loads up-front
        const int rr = rbase + sub + 5;
        bool ok = colok && (rr < H);
        nx[sub] = ok ? p1[rr * W + col] : 0.0f;
        ny[sub] = ok ? p2[rr * W + col] : 0.0f;
      }
#pragma unroll
      for (int sub = 0; sub < R; ++sub) {
        float x = nx[sub], y = ny[sub];
        float u = x + y, v = x - y;
        wu[10] = u; wv[10] = v; wuu[10] = u * u; wvv[10] = v * v;
        float iu = 0, iv = 0, iuu = 0, ivv = 0;
        float ou = 0, ov = 0, ouu = 0, ovv = 0;
#pragma unroll
        for (int k = 0; k < 11; ++k) {
          float ek = w.e[k];
          if (k >= 3 && k <= 7) {
            iu = fmaf(ek, wu[k], iu);   iv = fmaf(ek, wv[k], iv);
            iuu = fmaf(ek, wuu[k], iuu); ivv = fmaf(ek, wvv[k], ivv);
          } else {
            ou = fmaf(ek, wu[k], ou);   ov = fmaf(ek, wv[k], ov);
            ouu = fmaf(ek, wuu[k], ouu); ovv = fmaf(ek, wvv[k], ovv);
          }
        }
        sV[sub][0][t] = iu;
        sV[sub][1][t] = iv;
        sV[sub][2][t] = iuu;
        sV[sub][3][t] = ivv;
        sV[sub][4][t] = iu + ou;
        sV[sub][5][t] = iv + ov;
        sV[sub][6][t] = iuu + ouu;
        sV[sub][7][t] = ivv + ovv;
#pragma unroll
        for (int k = 0; k < 10; ++k) {             // shift (renamed by unroll)
          wu[k] = wu[k + 1]; wv[k] = wv[k + 1];
          wuu[k] = wuu[k + 1]; wvv[k] = wvv[k + 1];
        }
      }
    }
    __syncthreads();

    // ---- H phase: 256 slots (R rows x 32 groups x 4 cols), 1 per thread
    {
      const int sub = t >> 5;
      const int cb = (t & 31) * 4;     // first of 4 output cols (16B aligned)
      float iterSum = 0.0f;

      // Combo A: raw 11-tap conv over inner channels, SSIM with A constants
      {
        float a[4][4];
#pragma unroll
        for (int ch = 0; ch < 4; ++ch) {
          const float4* vp = (const float4*)&sV[sub][ch][cb];
          float f[16];
#pragma unroll
          for (int q = 0; q < 4; ++q) {
            float4 v = vp[q];
            f[4 * q] = v.x; f[4 * q + 1] = v.y;
            f[4 * q + 2] = v.z; f[4 * q + 3] = v.w;
          }
#pragma unroll
          for (int k = 0; k < 4; ++k) {
            float s = 0;
#pragma unroll
            for (int j = 0; j < 11; ++j) s = fmaf(w.e[j], f[k + j], s);
            a[k][ch] = s;
          }
        }
#pragma unroll
        for (int k = 0; k < 4; ++k)
          iterSum += ssim_uv(a[k][0], a[k][1], a[k][2], a[k][3], w.k2A, w.k1A);
      }
      // Combos C (full 11 raw) and B (inner 5 raw) share sums over full chans
      {
        float bi[4][4], co[4][4];
#pragma unroll
        for (int ch = 0; ch < 4; ++ch) {
          const float4* vp = (const float4*)&sV[sub][4 + ch][cb];
          float f[16];
#pragma unroll
          for (int q = 0; q < 4; ++q) {
            float4 v = vp[q];
            f[4 * q] = v.x; f[4 * q + 1] = v.y;
            f[4 * q + 2] = v.z; f[4 * q + 3] = v.w;
          }
#pragma unroll
          for (int k = 0; k < 4; ++k) {
            float ih = 0, oh = 0;
#pragma unroll
            for (int j = 0; j < 11; ++j) {
              if (j >= 3 && j <= 7) ih = fmaf(w.e[j], f[k + j], ih);
              else                  oh = fmaf(w.e[j], f[k + j], oh);
            }
            bi[k][ch] = ih;
            co[k][ch] = ih + oh;
          }
        }
#pragma unroll
        for (int k = 0; k < 4; ++k) {
          iterSum += ssim_uv(co[k][0], co[k][1], co[k][2], co[k][3],
                             w.k2C, w.k1C);
          iterSum += ssim_uv(bi[k][0], bi[k][1], bi[k][2], bi[k][3],
                             w.k2A, w.k1A);
        }
      }
      accT += (double)iterSum;
    }
    __syncthreads();
  }

  // block reduction (4 waves) -> one device atomic per block
#pragma unroll
  for (int off = 32; off > 0; off >>= 1) accT += __shfl_down(accT, off);
  const int wid = t >> 6;
  if ((t & 63) == 0) red[wid] = accT;
  __syncthreads();
  if (t == 0) {
    double s = 0.0;
    for (int k = 0; k < NTHREADS / 64; ++k) s += red[k];
    atomicAdd(acc, s);
  }
}

__global__ void finalize_kernel(const double* __restrict__ acc,
                                float* __restrict__ out) {
  out[0] = (float)(acc[0] * (1.0 / (3.0 * (double)NPLANE * H * W)));
}

extern "C" void kernel_launch(void* const* d_in, const int* in_sizes, int n_in,
                              void* d_out, int out_size, void* d_ws,
                              size_t ws_size, hipStream_t stream) {
  const float* img1 = (const float*)d_in[0];
  const float* img2 = (const float*)d_in[1];
  float* out = (float*)d_out;
  double* acc = (double*)d_ws;

  hipMemsetAsync(acc, 0, sizeof(double), stream);

  GaussW w;
  {
    double e64[11], S11 = 0.0, S5 = 0.0;
    for (int i = 0; i < 11; ++i) {
      double d = (double)(i - 5);
      e64[i] = exp(-d * d / 4.5);   // 2*sigma^2 = 4.5
      S11 += e64[i];
      if (i >= 3 && i <= 7) S5 += e64[i];
    }
    for (int i = 0; i < 11; ++i) w.e[i] = (float)e64[i];
    double sA = 1.0 / (S5 * S11);    // combos A and B
    double sC = 1.0 / (S11 * S11);   // combo C
    w.k2A = (float)(0.5 * sA);
    w.k1A = (float)(0.5 * sA * sA);
    w.k2C = (float)(0.5 * sC);
    w.k1C = (float)(0.5 * sC * sC);
  }

  dim3 grid(W / TW, H / BAND, NPLANE);   // 4 x 4 x 96 = 1536 blocks (4/CU)
  ssim_kernel<<<grid, NTHREADS, 0, stream>>>(img1, img2, acc, w);
  finalize_kernel<<<1, 1, 0, stream>>>(acc, out);
}

// Round 11
// 298.598 us; speedup vs baseline: 1.4780x; 1.1090x over previous
//
#include <hip/hip_runtime.h>
#include <math.h>

// Fused separable-Gaussian SSIM. N=32,C=3,H=W=512 fp32.
// Windows (5,11),(11,5),(11,11), sigma=1.5, zero padding.
// u/v reformulation (u=x+y, v=x-y) + PACKED fp32: channels are processed as
// float2 lane-pairs (u,v) and (uu,vv) so every conv FMA maps to
// v_pk_fma_f32 (VOP3P, 2 FMA/inst). LDS holds v2 elements; V-phase writes
// are ds_write_b64, H-phase reads are 7 x b128 per pair-channel (exactly the
// 14-wide v2 window). Raw (unnormalized) conv sums throughout; normalizer s
// folded exactly into SSIM rational coefficients (k1=.5*s^2, k2=.5*s).
//   A(5,11)=H11(inner)  B(11,5)=H5(full)  C(11,11)=H11(full)

#define H 512
#define W 512
#define NPLANE 96
#define TW 128          // output cols per block
#define PW 138          // TW + 10 halo cols
#define PWP 140         // padded LDS row of v2 (1120B, 16B-aligned)
#define BAND 128        // output rows per block
#define R 8             // rows per barrier iteration
#define NITER (BAND / R)
#define NTHREADS 256    // 4 waves; H phase has exactly 256 slots

typedef float v2 __attribute__((ext_vector_type(2)));

struct GaussW {
  float e[11];                  // raw exp(-d^2/4.5) weights
  float k2A, k1A, k2C, k1C;     // .5*s, .5*s^2 for combos A/B and C
};

// m = raw (mu_u, mu_v), s = raw (Muu, Mvv); k2=.5*scale, k1=.5*scale^2
__device__ __forceinline__ float ssim_uv(v2 m, v2 s, float k2, float k1) {
  const float C1 = 0.0001f;   // 0.01^2
  const float C2 = 0.0009f;   // 0.03^2
  v2 PQ = m * m;                       // v_pk_mul_f32
  float t1 = PQ.x - PQ.y, t2 = PQ.x + PQ.y;
  float n1 = fmaf(k1, t1, C1);
  float d1 = fmaf(k1, t2, C1);
  float u1 = s.x - s.y, u2 = s.x + s.y;
  float n2 = fmaf(k2, u1, fmaf(-k1, t1, C2));
  float d2 = fmaf(k2, u2, fmaf(-k1, t2, C2));
  return (n1 * n2) * __builtin_amdgcn_rcpf(d1 * d2);  // den >= C1*C2 > 0
}

__global__ __launch_bounds__(NTHREADS, 4) void ssim_kernel(
    const float* __restrict__ img1, const float* __restrict__ img2,
    double* __restrict__ acc, GaussW w) {
  // pair-channels: 0 = inner(u,v), 1 = inner(uu,vv), 2 = full(u,v), 3 = full(uu,vv)
  __shared__ __align__(16) v2 sV[R][4][PWP];      // 35.8 KB -> 4 blocks/CU
  __shared__ double red[NTHREADS / 64];

  const int t = threadIdx.x;
  const int tile = blockIdx.x, band = blockIdx.y, plane = blockIdx.z;
  const float* p1 = img1 + (size_t)plane * H * W;
  const float* p2 = img2 + (size_t)plane * H * W;
  const int c0 = tile * TW;
  const int r0 = band * BAND;
  const int col = c0 + t - 5;            // column owned in V phase
  const bool vact = (t < PW);
  const bool colok = vact && ((unsigned)col < (unsigned)W);

  // rolling windows: slot k = row (r-5+k) for current output row r
  v2 wUV[11], wQ[11];
#pragma unroll
  for (int k = 0; k < 10; ++k) {
    int rr = r0 - 5 + k;
    bool ok = colok && (rr >= 0);
    float x = ok ? p1[rr * W + col] : 0.0f;
    float y = ok ? p2[rr * W + col] : 0.0f;
    v2 uv; uv.x = x + y; uv.y = x - y;
    wUV[k] = uv; wQ[k] = uv * uv;
  }

  double accT = 0.0;
  for (int it = 0; it < NITER; ++it) {
    const int rbase = r0 + it * R;
    // ---- V phase: each column-thread produces R rows x 4 pair-channels
    if (vact) {
      float nx[R], ny[R];
#pragma unroll
      for (int sub = 0; sub < R; ++sub) {          // batch loads up-front
        const int rr = rbase + sub + 5;
        bool ok = colok && (rr < H);
        nx[sub] = ok ? p1[rr * W + col] : 0.0f;
        ny[sub] = ok ? p2[rr * W + col] : 0.0f;
      }
#pragma unroll
      for (int sub = 0; sub < R; ++sub) {
        v2 uv; uv.x = nx[sub] + ny[sub]; uv.y = nx[sub] - ny[sub];
        wUV[10] = uv; wQ[10] = uv * uv;
        v2 iUV = {0, 0}, iQ = {0, 0}, oUV = {0, 0}, oQ = {0, 0};
#pragma unroll
        for (int k = 0; k < 11; ++k) {
          v2 ek = {w.e[k], w.e[k]};
          if (k >= 3 && k <= 7) {
            iUV = __builtin_elementwise_fma(ek, wUV[k], iUV);
            iQ  = __builtin_elementwise_fma(ek, wQ[k], iQ);
          } else {
            oUV = __builtin_elementwise_fma(ek, wUV[k], oUV);
            oQ  = __builtin_elementwise_fma(ek, wQ[k], oQ);
          }
        }
        sV[sub][0][t] = iUV;
        sV[sub][1][t] = iQ;
        sV[sub][2][t] = iUV + oUV;
        sV[sub][3][t] = iQ + oQ;
#pragma unroll
        for (int k = 0; k < 10; ++k) {             // shift (renamed by unroll)
          wUV[k] = wUV[k + 1]; wQ[k] = wQ[k + 1];
        }
      }
    }
    __syncthreads();

    // ---- H phase: 256 slots (R rows x 32 groups x 4 cols), 1 per thread
    {
      const int sub = t >> 5;
      const int cb = (t & 31) * 4;     // first of 4 output cols
      float iterSum = 0.0f;

      v2 fUV[14], fQ[14];
      // Combo A: 11-tap conv over inner pair-channels, SSIM with A constants
      {
#pragma unroll
        for (int pc = 0; pc < 2; ++pc) {
          const float4* vp = (const float4*)&sV[sub][pc][cb];
          v2* dst = pc ? fQ : fUV;
#pragma unroll
          for (int q = 0; q < 7; ++q) {
            float4 r4 = vp[q];
            v2 lo; lo.x = r4.x; lo.y = r4.y;
            v2 hi; hi.x = r4.z; hi.y = r4.w;
            dst[2 * q] = lo; dst[2 * q + 1] = hi;
          }
        }
#pragma unroll
        for (int k = 0; k < 4; ++k) {
          v2 aUV = {0, 0}, aQ = {0, 0};
#pragma unroll
          for (int j = 0; j < 11; ++j) {
            v2 ej = {w.e[j], w.e[j]};
            aUV = __builtin_elementwise_fma(ej, fUV[k + j], aUV);
            aQ  = __builtin_elementwise_fma(ej, fQ[k + j], aQ);
          }
          iterSum += ssim_uv(aUV, aQ, w.k2A, w.k1A);
        }
      }
      // Combos C (full 11) and B (inner 5) share inner/outer over full chans
      {
#pragma unroll
        for (int pc = 0; pc < 2; ++pc) {
          const float4* vp = (const float4*)&sV[sub][2 + pc][cb];
          v2* dst = pc ? fQ : fUV;
#pragma unroll
          for (int q = 0; q < 7; ++q) {
            float4 r4 = vp[q];
            v2 lo; lo.x = r4.x; lo.y = r4.y;
            v2 hi; hi.x = r4.z; hi.y = r4.w;
            dst[2 * q] = lo; dst[2 * q + 1] = hi;
          }
        }
#pragma unroll
        for (int k = 0; k < 4; ++k) {
          v2 biUV = {0, 0}, biQ = {0, 0}, boUV = {0, 0}, boQ = {0, 0};
#pragma unroll
          for (int j = 0; j < 11; ++j) {
            v2 ej = {w.e[j], w.e[j]};
            if (j >= 3 && j <= 7) {
              biUV = __builtin_elementwise_fma(ej, fUV[k + j], biUV);
              biQ  = __builtin_elementwise_fma(ej, fQ[k + j], biQ);
            } else {
              boUV = __builtin_elementwise_fma(ej, fUV[k + j], boUV);
              boQ  = __builtin_elementwise_fma(ej, fQ[k + j], boQ);
            }
          }
          iterSum += ssim_uv(biUV + boUV, biQ + boQ, w.k2C, w.k1C);
          iterSum += ssim_uv(biUV, biQ, w.k2A, w.k1A);
        }
      }
      accT += (double)iterSum;
    }
    __syncthreads();
  }

  // block reduction (4 waves) -> one device atomic per block
#pragma unroll
  for (int off = 32; off > 0; off >>= 1) accT += __shfl_down(accT, off);
  const int wid = t >> 6;
  if ((t & 63) == 0) red[wid] = accT;
  __syncthreads();
  if (t == 0) {
    double s = 0.0;
    for (int k = 0; k < NTHREADS / 64; ++k) s += red[k];
    atomicAdd(acc, s);
  }
}

__global__ void finalize_kernel(const double* __restrict__ acc,
                                float* __restrict__ out) {
  out[0] = (float)(acc[0] * (1.0 / (3.0 * (double)NPLANE * H * W)));
}

extern "C" void kernel_launch(void* const* d_in, const int* in_sizes, int n_in,
                              void* d_out, int out_size, void* d_ws,
                              size_t ws_size, hipStream_t stream) {
  const float* img1 = (const float*)d_in[0];
  const float* img2 = (const float*)d_in[1];
  float* out = (float*)d_out;
  double* acc = (double*)d_ws;

  hipMemsetAsync(acc, 0, sizeof(double), stream);

  GaussW w;
  {
    double e64[11], S11 = 0.0, S5 = 0.0;
    for (int i = 0; i < 11; ++i) {
      double d = (double)(i - 5);
      e64[i] = exp(-d * d / 4.5);   // 2*sigma^2 = 4.5
      S11 += e64[i];
      if (i >= 3 && i <= 7) S5 += e64[i];
    }
    for (int i = 0; i < 11; ++i) w.e[i] = (float)e64[i];
    double sA = 1.0 / (S5 * S11);    // combos A and B
    double sC = 1.0 / (S11 * S11);   // combo C
    w.k2A = (float)(0.5 * sA);
    w.k1A = (float)(0.5 * sA * sA);
    w.k2C = (float)(0.5 * sC);
    w.k1C = (float)(0.5 * sC * sC);
  }

  dim3 grid(W / TW, H / BAND, NPLANE);   // 4 x 4 x 96 = 1536 blocks (4/CU)
  ssim_kernel<<<grid, NTHREADS, 0, stream>>>(img1, img2, acc, w);
  finalize_kernel<<<1, 1, 0, stream>>>(acc, out);
}